// Round 2
// baseline (160.253 us; speedup 1.0000x reference)
//
#include <hip/hip_runtime.h>

// CRS rate-and-state model: per-row sequential recurrence parallelized via
// Mobius-transform composition. Each step t maps R -> (et*R)/(1 + c*R) with
// c = (eta/sd)*(et-1). Maps [[a,0],[c,1]] compose associatively, so we
// wave-scan (A,C) pairs: one wave per row, 64 lanes x 8 steps = 512-step tiles.
// R2: STEPS 4->8 (halves shuffle-scan rounds) + manual next-tile register
// prefetch (hides HBM latency under tile compute; compiler wouldn't pipeline
// on its own at VGPR=32).

#define C_TNSR  0.001f
#define C_TSSR  0.002f
#define C_SIGMA 50.0f
#define C_BIOT  0.3f
#define C_R0    0.0001f
#define C_N0    0.0001f

constexpr int B = 8192;
constexpr int T = 4096;
constexpr int STEPS = 8;
constexpr int TILE  = 64 * STEPS;  // 512
constexpr int NTILE = T / TILE;    // 8

typedef float f4 __attribute__((ext_vector_type(4)));

__global__ __launch_bounds__(256, 4)
void crs_scan_kernel(const float* __restrict__ params,
                     const float* __restrict__ p,
                     const float* __restrict__ dpdt,
                     const float* __restrict__ dtv,
                     float* __restrict__ Rt,
                     float* __restrict__ Nt)
{
    const int lane = threadIdx.x & 63;
    const int b = (int)((blockIdx.x * blockDim.x + threadIdx.x) >> 6);

    const float mu  = params[b * 3 + 0];
    const float rc  = params[b * 3 + 1];
    const float rf  = params[b * 3 + 2];
    const float eta = 1.0f / rf;

    const float* __restrict__ prow = p    + (size_t)b * T;
    const float* __restrict__ drow = dpdt + (size_t)b * T;
    const float* __restrict__ trow = dtv  + (size_t)b * T;
    float* __restrict__ Rrow = Rt + (size_t)b * (T + 1) + 1;
    float* __restrict__ Nrow = Nt + (size_t)b * (T + 1) + 1;

    if (lane == 0) { Rrow[-1] = C_R0; Nrow[-1] = C_N0; }

    float Rc = C_R0;   // running R carry
    float Nc = C_N0;   // running Nt carry (cumsum incl. N0)

    const int l8 = lane * STEPS;

    // current-tile input registers (double-buffered by rotation)
    f4 p0 = *(const f4*)(prow + l8);
    f4 p1 = *(const f4*)(prow + l8 + 4);
    f4 d0 = *(const f4*)(drow + l8);
    f4 d1 = *(const f4*)(drow + l8 + 4);
    f4 t0 = *(const f4*)(trow + l8);
    f4 t1 = *(const f4*)(trow + l8 + 4);

    for (int tile = 0; tile < NTILE; ++tile) {
        const int off = tile * TILE + l8;

        // prefetch next tile (clamped on last iter -> L1-hit re-loads, no branch)
        const int noff = (tile + 1 < NTILE) ? (off + TILE) : off;
        f4 np0 = *(const f4*)(prow + noff);
        f4 np1 = *(const f4*)(prow + noff + 4);
        f4 nd0 = *(const f4*)(drow + noff);
        f4 nd1 = *(const f4*)(drow + noff + 4);
        f4 nt0 = *(const f4*)(trow + noff);
        f4 nt1 = *(const f4*)(trow + noff + 4);

        float et[STEPS], cc[STEPS], kk[STEPS];
        float A = 1.0f, C = 0.0f;
#pragma unroll
        for (int j = 0; j < STEPS; ++j) {
            float pv = (j < 4) ? p0[j] : p1[j - 4];
            float dv = (j < 4) ? d0[j] : d1[j - 4];
            float tv = (j < 4) ? t0[j] : t1[j - 4];
            float sd   = C_TSSR - mu * (C_TNSR - dv);
            float asig = rc * (C_SIGMA - C_BIOT * pv);
            float e    = __expf(__fdividef(sd * tv, asig));
            float c    = __fdividef(eta * (e - 1.0f), sd);
            et[j] = e;
            cc[j] = c;
            kk[j] = asig * rf;           // asig/eta
            C = fmaf(c, A, C);           // compose step j after (A,C)
            A = A * e;
        }

        // wave-inclusive scan of Mobius pairs (A,C): A=A*Ap ; C=C*Ap+Cp
#pragma unroll
        for (int o = 1; o < 64; o <<= 1) {
            float Ap = __shfl_up(A, (unsigned)o, 64);
            float Cp = __shfl_up(C, (unsigned)o, 64);
            if (lane >= o) { C = fmaf(C, Ap, Cp); A = A * Ap; }
        }
        // exclusive prefix for this lane's segment
        float Ae = __shfl_up(A, 1u, 64);
        float Ce = __shfl_up(C, 1u, 64);
        if (lane == 0) { Ae = 1.0f; Ce = 0.0f; }

        // R entering this lane's segment
        float Rp = __fdividef(Ae * Rc, fmaf(Ce, Rc, 1.0f));

        // replay the 8 steps exactly; store R as we go, keep local N cumsum
        float nn[STEPS];
        float ns = 0.0f;
#pragma unroll
        for (int j = 0; j < STEPS; ++j) {
            float den = fmaf(cc[j], Rp, 1.0f);   // == 1 - (eta*R/sd)*(1-et)
            ns += kk[j] * __logf(den);
            nn[j] = ns;
            Rp = __fdividef(Rp * et[j], den);
            Rrow[off + j] = Rp;
        }

        // wave-inclusive prefix sum of per-lane N totals
        float S = ns;
#pragma unroll
        for (int o = 1; o < 64; o <<= 1) {
            float Sp = __shfl_up(S, (unsigned)o, 64);
            if (lane >= o) S += Sp;
        }
        float base = Nc + (S - ns);

#pragma unroll
        for (int j = 0; j < STEPS; ++j) Nrow[off + j] = base + nn[j];

        // carries from lane 63
        Rc = __shfl(Rp, 63, 64);
        Nc = Nc + __shfl(S, 63, 64);

        // rotate prefetched buffers in
        p0 = np0; p1 = np1; d0 = nd0; d1 = nd1; t0 = nt0; t1 = nt1;
    }
}

extern "C" void kernel_launch(void* const* d_in, const int* in_sizes, int n_in,
                              void* d_out, int out_size, void* d_ws, size_t ws_size,
                              hipStream_t stream)
{
    const float* params = (const float*)d_in[0];
    const float* p      = (const float*)d_in[1];
    const float* dpdt   = (const float*)d_in[2];
    const float* dtv    = (const float*)d_in[3];

    float* Rt = (float*)d_out;                       // B*(T+1)
    float* Nt = (float*)d_out + (size_t)B * (T + 1); // B*(T+1)

    const int block = 256;                 // 4 waves = 4 rows per block
    const int grid  = (B * 64) / block;    // 2048 blocks
    crs_scan_kernel<<<grid, block, 0, stream>>>(params, p, dpdt, dtv, Rt, Nt);
}

// Round 3
// 147.992 us; speedup vs baseline: 1.0829x; 1.0829x over previous
//
#include <hip/hip_runtime.h>

// CRS rate-and-state model: per-row recurrence parallelized via Mobius map
// composition (R -> et*R/(1+c*R); maps [[a,0],[c,1]] compose associatively).
// One wave per row, 64 lanes x 8 steps = 512-step tiles, wave shuffle-scan.
// R3: (1) prefetch pinned with sched_barrier(0) so loads stay issued a full
// tile ahead (R2's rotation was folded away at VGPR=40); (2) stores routed
// through a per-wave XOR-swizzled LDS bounce so each global store instruction
// writes 64 CONSECUTIVE dwords (dense cachelines) instead of stride-32B
// scatter. Direct f4 stores impossible: row base b*4097+1 is unaligned.

#define C_TNSR  0.001f
#define C_TSSR  0.002f
#define C_SIGMA 50.0f
#define C_BIOT  0.3f
#define C_R0    0.0001f
#define C_N0    0.0001f

constexpr int B = 8192;
constexpr int T = 4096;
constexpr int STEPS = 8;
constexpr int TILE  = 64 * STEPS;   // 512
constexpr int NTILE = T / TILE;     // 8
constexpr int WPB   = 4;            // waves per block

typedef float f4 __attribute__((ext_vector_type(4)));

__global__ __launch_bounds__(256)
void crs_scan_kernel(const float* __restrict__ params,
                     const float* __restrict__ p,
                     const float* __restrict__ dpdt,
                     const float* __restrict__ dtv,
                     float* __restrict__ Rt,
                     float* __restrict__ Nt)
{
    __shared__ float sb[WPB][2][TILE];   // per-wave store-realign bounce (16 KB)

    const int lane = threadIdx.x & 63;
    const int wid  = (threadIdx.x >> 6) & (WPB - 1);
    const int b    = (int)((blockIdx.x * blockDim.x + threadIdx.x) >> 6);

    const float mu  = params[b * 3 + 0];
    const float rc  = params[b * 3 + 1];
    const float rf  = params[b * 3 + 2];
    const float eta = 1.0f / rf;

    const float* __restrict__ prow = p    + (size_t)b * T;
    const float* __restrict__ drow = dpdt + (size_t)b * T;
    const float* __restrict__ trow = dtv  + (size_t)b * T;
    float* __restrict__ Rrow = Rt + (size_t)b * (T + 1) + 1;
    float* __restrict__ Nrow = Nt + (size_t)b * (T + 1) + 1;

    if (lane == 0) { Rrow[-1] = C_R0; Nrow[-1] = C_N0; }

    float* __restrict__ lr = &sb[wid][0][0];
    float* __restrict__ ln = &sb[wid][1][0];

    float Rc = C_R0;   // running R carry
    float Nc = C_N0;   // running Nt cumsum carry (incl. N0)

    const int l8 = lane * STEPS;

    // current-tile input registers
    f4 p0 = *(const f4*)(prow + l8);
    f4 p1 = *(const f4*)(prow + l8 + 4);
    f4 d0 = *(const f4*)(drow + l8);
    f4 d1 = *(const f4*)(drow + l8 + 4);
    f4 t0 = *(const f4*)(trow + l8);
    f4 t1 = *(const f4*)(trow + l8 + 4);

    for (int tile = 0; tile < NTILE; ++tile) {
        const int toff = tile * TILE;

        // ---- prefetch next tile; pin issue point so it can't be sunk ----
        const int noff = (tile + 1 < NTILE) ? (toff + TILE + l8) : (toff + l8);
        f4 np0 = *(const f4*)(prow + noff);
        f4 np1 = *(const f4*)(prow + noff + 4);
        f4 nd0 = *(const f4*)(drow + noff);
        f4 nd1 = *(const f4*)(drow + noff + 4);
        f4 nt0 = *(const f4*)(trow + noff);
        f4 nt1 = *(const f4*)(trow + noff + 4);
        __builtin_amdgcn_sched_barrier(0);

        // ---- build per-step Mobius coefficients and local composition ----
        float et[STEPS], cc[STEPS], kk[STEPS];
        float A = 1.0f, C = 0.0f;
#pragma unroll
        for (int j = 0; j < STEPS; ++j) {
            float pv = (j < 4) ? p0[j] : p1[j - 4];
            float dv = (j < 4) ? d0[j] : d1[j - 4];
            float tv = (j < 4) ? t0[j] : t1[j - 4];
            float sd   = C_TSSR - mu * (C_TNSR - dv);
            float asig = rc * (C_SIGMA - C_BIOT * pv);
            float e    = __expf(__fdividef(sd * tv, asig));
            float c    = __fdividef(eta * (e - 1.0f), sd);
            et[j] = e;
            cc[j] = c;
            kk[j] = asig * rf;           // asig/eta
            C = fmaf(c, A, C);           // compose step j after (A,C)
            A = A * e;
        }

        // ---- wave-inclusive scan of (A,C): A=A*Ap ; C=C*Ap+Cp ----
#pragma unroll
        for (int o = 1; o < 64; o <<= 1) {
            float Ap = __shfl_up(A, (unsigned)o, 64);
            float Cp = __shfl_up(C, (unsigned)o, 64);
            if (lane >= o) { C = fmaf(C, Ap, Cp); A = A * Ap; }
        }
        float Ae = __shfl_up(A, 1u, 64);
        float Ce = __shfl_up(C, 1u, 64);
        if (lane == 0) { Ae = 1.0f; Ce = 0.0f; }

        // R entering this lane's 8-step segment
        float Rp = __fdividef(Ae * Rc, fmaf(Ce, Rc, 1.0f));

        // ---- replay: exact per-step R (to LDS, swizzled) + local N cumsum ----
        float nn[STEPS];
        float ns = 0.0f;
#pragma unroll
        for (int j = 0; j < STEPS; ++j) {
            float den = fmaf(cc[j], Rp, 1.0f);   // == 1 - (eta*R/sd)*(1-et)
            ns += kk[j] * __logf(den);
            nn[j] = ns;
            Rp = __fdividef(Rp * et[j], den);
            lr[j * 64 + (lane ^ (8 * j))] = Rp;  // XOR swizzle: 2-way banks, free
        }

        // ---- wave prefix sum of per-lane N totals ----
        float S = ns;
#pragma unroll
        for (int o = 1; o < 64; o <<= 1) {
            float Sp = __shfl_up(S, (unsigned)o, 64);
            if (lane >= o) S += Sp;
        }
        float base = Nc + (S - ns);
#pragma unroll
        for (int j = 0; j < STEPS; ++j)
            ln[j * 64 + (lane ^ (8 * j))] = base + nn[j];

        // ---- realigned stores: 64 consecutive dwords per instruction ----
        // element m = q*64+lane of this tile lives at lds[jp*64 + (lp^(8*jp))]
        // with lp = m>>3 (owner lane), jp = m&7 (step).
#pragma unroll
        for (int q = 0; q < 8; ++q) {
            const int lp = q * 8 + (lane >> 3);
            const int jp = lane & 7;
            const int sidx = jp * 64 + (lp ^ (8 * jp));
            Rrow[toff + q * 64 + lane] = lr[sidx];
            Nrow[toff + q * 64 + lane] = ln[sidx];
        }

        // ---- carries from lane 63, rotate prefetched inputs in ----
        Rc = __shfl(Rp, 63, 64);
        Nc = Nc + __shfl(S, 63, 64);
        p0 = np0; p1 = np1; d0 = nd0; d1 = nd1; t0 = nt0; t1 = nt1;
    }
}

extern "C" void kernel_launch(void* const* d_in, const int* in_sizes, int n_in,
                              void* d_out, int out_size, void* d_ws, size_t ws_size,
                              hipStream_t stream)
{
    const float* params = (const float*)d_in[0];
    const float* p      = (const float*)d_in[1];
    const float* dpdt   = (const float*)d_in[2];
    const float* dtv    = (const float*)d_in[3];

    float* Rt = (float*)d_out;                       // B*(T+1)
    float* Nt = (float*)d_out + (size_t)B * (T + 1); // B*(T+1)

    const int block = 256;                 // 4 waves = 4 rows per block
    const int grid  = (B * 64) / block;    // 2048 blocks
    crs_scan_kernel<<<grid, block, 0, stream>>>(params, p, dpdt, dtv, Rt, Nt);
}